// Round 7
// baseline (138.489 us; speedup 1.0000x reference)
//
#include <hip/hip_runtime.h>

typedef unsigned short u16;
typedef unsigned int u32;
typedef float f32x4 __attribute__((ext_vector_type(4)));
typedef short bf16x8 __attribute__((ext_vector_type(8)));

#define U_M 0.8f
#define L_M 0.45f
#define U_A 110.0f
#define L_A 10.0f
#define LAMBDA_G 35.0f
#define SCALEF 64.0f

__device__ __forceinline__ u16 f2bf(float f) {
  u32 u = __builtin_bit_cast(u32, f);
  u32 r = (u + 0x7fffu + ((u >> 16) & 1u)) >> 16;
  return (u16)r;
}

__device__ __forceinline__ u32 cvtpk(float lo, float hi) {
  u32 r;
  asm("v_cvt_pk_bf16_f32 %0, %1, %2" : "=v"(r) : "v"(lo), "v"(hi));
  return r;
}

// ---- normalize rows of x, store bf16. one wave per row, 4 rows/block ----
__global__ void xnorm_kernel(const float* __restrict__ x, u16* __restrict__ xn, int K) {
  int row = blockIdx.x * 4 + (threadIdx.x >> 6);
  int l = threadIdx.x & 63;
  const float4* p = reinterpret_cast<const float4*>(x + (size_t)row * K) + l * 2;
  float4 a = p[0], b = p[1];
  float s = a.x*a.x + a.y*a.y + a.z*a.z + a.w*a.w
          + b.x*b.x + b.y*b.y + b.z*b.z + b.w*b.w;
  #pragma unroll
  for (int m = 32; m >= 1; m >>= 1) s += __shfl_xor(s, m);
  float inv = rsqrtf(fmaxf(s, 1e-24f));
  u32 q0 = (u32)f2bf(a.x*inv) | ((u32)f2bf(a.y*inv) << 16);
  u32 q1 = (u32)f2bf(a.z*inv) | ((u32)f2bf(a.w*inv) << 16);
  u32 q2 = (u32)f2bf(b.x*inv) | ((u32)f2bf(b.y*inv) << 16);
  u32 q3 = (u32)f2bf(b.z*inv) | ((u32)f2bf(b.w*inv) << 16);
  *reinterpret_cast<uint4*>(xn + (size_t)row * K + l * 8) = make_uint4(q0, q1, q2, q3);
}

// ---- f32-exact target-class cosine per sample ----
__global__ void tgt_kernel(const float* __restrict__ x, const float* __restrict__ W,
                           const int* __restrict__ labels, float* __restrict__ tgtcos, int K) {
  int b = blockIdx.x;
  int l = threadIdx.x;
  int lab = labels[b];
  int labc = lab < 0 ? 0 : lab;
  const float4* px = reinterpret_cast<const float4*>(x + (size_t)b * K) + l * 2;
  const float4* pw = reinterpret_cast<const float4*>(W + (size_t)labc * K) + l * 2;
  float4 a0 = px[0], a1 = px[1], w0 = pw[0], w1 = pw[1];
  float dot = a0.x*w0.x + a0.y*w0.y + a0.z*w0.z + a0.w*w0.w
            + a1.x*w1.x + a1.y*w1.y + a1.z*w1.z + a1.w*w1.w;
  float sx = a0.x*a0.x + a0.y*a0.y + a0.z*a0.z + a0.w*a0.w
           + a1.x*a1.x + a1.y*a1.y + a1.z*a1.z + a1.w*a1.w;
  float sw = w0.x*w0.x + w0.y*w0.y + w0.z*w0.z + w0.w*w0.w
           + w1.x*w1.x + w1.y*w1.y + w1.z*w1.z + w1.w*w1.w;
  #pragma unroll
  for (int m = 32; m >= 1; m >>= 1) {
    dot += __shfl_xor(dot, m);
    sx  += __shfl_xor(sx, m);
    sw  += __shfl_xor(sw, m);
  }
  if (l == 0) {
    float cv = dot * rsqrtf(fmaxf(sx, 1e-24f)) * rsqrtf(fmaxf(sw, 1e-24f));
    tgtcos[b] = fminf(fmaxf(cv, -1.f), 1.f);
  }
}

// ---- tall fused GEMM: one block owns ALL of M (512) x 128 N-cols ----
// Wave w owns rows [w*64, w*64+64) x 128 cols: acc[4][8], 64 MFMA per K-step.
// Each W panel is read by exactly ONE block -> W streamed from HBM once.
__global__ __launch_bounds__(512, 2) void gemm_tall(
    const u16* __restrict__ xn, const float* __restrict__ W,
    const int* __restrict__ labels,
    float* __restrict__ partials, int C, int K, int M) {
  __shared__ u16 sA[2][512 * 64];   // 2 x 64 KB
  __shared__ u16 sB[128 * 64];      // 16 KB
  __shared__ float sIw[128];
  __shared__ int slab[512];

  const int bn = blockIdx.x;
  const int n0 = bn * 128;
  const int t = threadIdx.x;
  const int l = t & 63;
  const int w = t >> 6;             // wave id 0..7 -> M-rows [w*64, w*64+64)

  slab[t] = labels[t];

  // B staging geometry (coalesced): 16 lanes per row chunk of 256B.
  const int c4 = t & 15;            // float4 index within row's 64-float K-window
  const int rowL = t >> 4;          // 0..31, 4 passes of 32 rows
  const float* wp[4];
  #pragma unroll
  for (int p = 0; p < 4; ++p) {
    int rr = n0 + p * 32 + rowL;
    rr = rr < C ? rr : C - 1;
    wp[p] = W + (size_t)rr * K + c4 * 4;
  }
  float ssq[4] = {0.f, 0.f, 0.f, 0.f};

  const int nkt = K >> 6;           // 8
  float4 v[4];

  // --- prologue: stage tile 0 ---
  #pragma unroll
  for (int p = 0; p < 4; ++p) v[p] = *reinterpret_cast<const float4*>(wp[p]);
  #pragma unroll
  for (int i = 0; i < 8; ++i) {
    int L = i * 512 + t;
    int rr = L >> 3;                // 0..511
    int cs = (L & 7) ^ (rr & 7);
    const u16* src = xn + (size_t)rr * K + cs * 8;
    __builtin_amdgcn_global_load_lds(
        (const __attribute__((address_space(1))) void*)src,
        (__attribute__((address_space(3))) void*)(sA[0] + (size_t)(i * 512 + (t & 448)) * 8),
        16, 0, 0);
  }
  #pragma unroll
  for (int p = 0; p < 4; ++p) {
    float4 f = v[p];
    ssq[p] += f.x*f.x + f.y*f.y + f.z*f.z + f.w*f.w;
    int rr = p * 32 + rowL;
    uint2 pk = make_uint2(cvtpk(f.x, f.y), cvtpk(f.z, f.w));
    *reinterpret_cast<uint2*>(sB + rr * 64 + (((c4 >> 1) ^ (rr & 7)) * 8) + (c4 & 1) * 4) = pk;
  }
  __syncthreads();

  f32x4 acc[4][8] = {};
  for (int kt = 0; kt < nkt; ++kt) {
    const bool pf = (kt + 1) < nkt;
    const u16* aCur = sA[kt & 1];

    // --- issue next-tile loads BEFORE MFMA (latency hides under compute) ---
    if (pf) {
      const int k1 = (kt + 1) << 6;
      #pragma unroll
      for (int p = 0; p < 4; ++p) v[p] = *reinterpret_cast<const float4*>(wp[p] + k1);
      u16* aNxt = sA[(kt + 1) & 1];
      #pragma unroll
      for (int i = 0; i < 8; ++i) {
        int L = i * 512 + t;
        int rr = L >> 3;
        int cs = (L & 7) ^ (rr & 7);
        const u16* src = xn + (size_t)rr * K + k1 + cs * 8;
        __builtin_amdgcn_global_load_lds(
            (const __attribute__((address_space(1))) void*)src,
            (__attribute__((address_space(3))) void*)(aNxt + (size_t)(i * 512 + (t & 448)) * 8),
            16, 0, 0);
      }
    }

    // --- MFMA phase: 64 MFMA per wave per K-step ---
    #pragma unroll
    for (int ks = 0; ks < 2; ++ks) {
      bf16x8 af[4], bfr[8];
      #pragma unroll
      for (int mi = 0; mi < 4; ++mi) {
        int row = w * 64 + mi * 16 + (l & 15);
        int ch = ks * 4 + (l >> 4);
        af[mi] = *reinterpret_cast<const bf16x8*>(aCur + row * 64 + ((ch ^ (row & 7)) * 8));
      }
      #pragma unroll
      for (int ni = 0; ni < 8; ++ni) {
        int row = ni * 16 + (l & 15);
        int ch = ks * 4 + (l >> 4);
        bfr[ni] = *reinterpret_cast<const bf16x8*>(sB + row * 64 + ((ch ^ (row & 7)) * 8));
      }
      #pragma unroll
      for (int mi = 0; mi < 4; ++mi)
        #pragma unroll
        for (int ni = 0; ni < 8; ++ni)
          acc[mi][ni] = __builtin_amdgcn_mfma_f32_16x16x32_bf16(af[mi], bfr[ni], acc[mi][ni], 0, 0, 0);
    }

    __syncthreads();  // waves done reading sB; prefetch drained (covered by MFMA)

    // --- convert prefetched W into sB ---
    if (pf) {
      #pragma unroll
      for (int p = 0; p < 4; ++p) {
        float4 f = v[p];
        ssq[p] += f.x*f.x + f.y*f.y + f.z*f.z + f.w*f.w;
        int rr = p * 32 + rowL;
        uint2 pk = make_uint2(cvtpk(f.x, f.y), cvtpk(f.z, f.w));
        *reinterpret_cast<uint2*>(sB + rr * 64 + (((c4 >> 1) ^ (rr & 7)) * 8) + (c4 & 1) * 4) = pk;
      }
    }
    __syncthreads();  // ds_writes visible for next MFMA phase
  }

  // finalize inverse col norms (16-lane reduce, lanes share row)
  #pragma unroll
  for (int p = 0; p < 4; ++p) {
    float s = ssq[p];
    s += __shfl_xor(s, 1);
    s += __shfl_xor(s, 2);
    s += __shfl_xor(s, 4);
    s += __shfl_xor(s, 8);
    if (c4 == 0) sIw[p * 32 + rowL] = rsqrtf(fmaxf(s, 1e-24f));
  }
  __syncthreads();

  // epilogue: cos -> exp(64 cos - 64), zero target column, per-row reduce.
  // Each row is owned by exactly one wave -> direct global write, no cross-wave LDS.
  float iw[8]; int colv[8];
  #pragma unroll
  for (int ni = 0; ni < 8; ++ni) {
    int cl = ni * 16 + (l & 15);
    colv[ni] = n0 + cl;
    iw[ni] = sIw[cl];
  }
  #pragma unroll
  for (int mi = 0; mi < 4; ++mi) {
    #pragma unroll
    for (int rg = 0; rg < 4; ++rg) {
      int row_l = w * 64 + mi * 16 + ((l >> 4) << 2) + rg;
      int labr = slab[row_l];
      float rs = 0.f;
      #pragma unroll
      for (int ni = 0; ni < 8; ++ni) {
        float cv = acc[mi][ni][rg] * iw[ni];
        cv = fminf(fmaxf(cv, -1.f), 1.f);
        float e = __expf(SCALEF * cv - SCALEF);
        bool keep = (colv[ni] < C) && (colv[ni] != labr);
        rs += keep ? e : 0.f;
      }
      rs += __shfl_xor(rs, 1);
      rs += __shfl_xor(rs, 2);
      rs += __shfl_xor(rs, 4);
      rs += __shfl_xor(rs, 8);
      if ((l & 15) == 0) partials[(size_t)bn * M + row_l] = rs;
    }
  }
}

// ---- deterministic reduction of partials over N-blocks ----
__global__ void rowreduce_kernel(const float* __restrict__ partials, float* __restrict__ rowsum,
                                 int NBN, int M) {
  int b = blockIdx.x, t = threadIdx.x;
  float s = 0.f;
  for (int i = t; i < NBN; i += 256) s += partials[(size_t)i * M + b];
  __shared__ float sh[256];
  sh[t] = s; __syncthreads();
  for (int off = 128; off >= 1; off >>= 1) {
    if (t < off) sh[t] += sh[t + off];
    __syncthreads();
  }
  if (t == 0) rowsum[b] = sh[0];
}

// ---- final: per-sample nll + G-loss, single block ----
__global__ void final_kernel(const float* __restrict__ rowsum, const float* __restrict__ tgtcos,
                             const float* __restrict__ x_norm, const int* __restrict__ labels,
                             float* __restrict__ out, int Bn) {
  int t = threadIdx.x;
  float nll = 0.f, g = 0.f, vld = 0.f;
  if (t < Bn) {
    float a = x_norm[t];
    g = a * (1.0f / (U_A * U_A)) + 1.0f / a;
    int lab = labels[t];
    bool valid = (lab != -1);
    if (valid) {
      float ct = tgtcos[t];
      float margin = ((U_M - L_M) / (U_A - L_A)) * (a - L_A) + L_M;
      float theta = acosf(ct) + margin;
      float tl = SCALEF * cosf(theta);
      float se = rowsum[t] + __expf(tl - SCALEF);
      float lse = SCALEF + logf(se);
      nll = lse - tl;
      vld = 1.f;
    }
  }
  __shared__ float s1[512], s2[512], s3[512];
  s1[t] = nll; s2[t] = g; s3[t] = vld;
  __syncthreads();
  for (int off = 256; off >= 1; off >>= 1) {
    if (t < off) { s1[t] += s1[t + off]; s2[t] += s2[t + off]; s3[t] += s3[t + off]; }
    __syncthreads();
  }
  if (t == 0) {
    float ce = s1[0] / fmaxf(s3[0], 1.f);
    out[0] = ce + LAMBDA_G * (s2[0] / (float)Bn);
  }
}

extern "C" void kernel_launch(void* const* d_in, const int* in_sizes, int n_in,
                              void* d_out, int out_size, void* d_ws, size_t ws_size,
                              hipStream_t stream) {
  const float* x      = (const float*)d_in[0];
  const float* x_norm = (const float*)d_in[1];
  const int*   labels = (const int*)d_in[2];
  const float* W      = (const float*)d_in[3];
  float* out = (float*)d_out;

  const int B = in_sizes[1];             // 512
  const int D = in_sizes[0] / B;         // 512
  const int C = in_sizes[3] / D;         // 100000
  const int NBN = (C + 127) / 128;       // 782

  char* ws = (char*)d_ws;
  size_t o_xn   = 0;
  size_t o_tgt  = o_xn + (size_t)B * D * 2;
  size_t o_rows = o_tgt + (size_t)B * 4;
  size_t o_part = o_rows + (size_t)B * 4;

  u16*   xn       = (u16*)(ws + o_xn);
  float* tgtcos   = (float*)(ws + o_tgt);
  float* rowsum   = (float*)(ws + o_rows);
  float* partials = (float*)(ws + o_part);

  hipLaunchKernelGGL(xnorm_kernel, dim3(B / 4), dim3(256), 0, stream, x, xn, D);
  hipLaunchKernelGGL(tgt_kernel, dim3(B), dim3(64), 0, stream, x, W, labels, tgtcos, D);
  hipLaunchKernelGGL(gemm_tall, dim3(NBN), dim3(512), 0, stream,
                     xn, W, labels, partials, C, D, B);
  hipLaunchKernelGGL(rowreduce_kernel, dim3(B), dim3(256), 0, stream, partials, rowsum, NBN, B);
  hipLaunchKernelGGL(final_kernel, dim3(1), dim3(B), 0, stream, rowsum, tgtcos, x_norm, labels, out, B);
}

// Round 8
// 121.651 us; speedup vs baseline: 1.1384x; 1.1384x over previous
//
#include <hip/hip_runtime.h>

typedef unsigned short u16;
typedef unsigned int u32;
typedef float f32x4 __attribute__((ext_vector_type(4)));
typedef short bf16x8 __attribute__((ext_vector_type(8)));

#define U_M 0.8f
#define L_M 0.45f
#define U_A 110.0f
#define L_A 10.0f
#define LAMBDA_G 35.0f
#define SCALEF 64.0f

__device__ __forceinline__ u16 f2bf(float f) {
  u32 u = __builtin_bit_cast(u32, f);
  u32 r = (u + 0x7fffu + ((u >> 16) & 1u)) >> 16;
  return (u16)r;
}

__device__ __forceinline__ u32 cvtpk(float lo, float hi) {
  u32 r;
  asm("v_cvt_pk_bf16_f32 %0, %1, %2" : "=v"(r) : "v"(lo), "v"(hi));
  return r;
}

// ---- normalize rows of x, store bf16. one wave per row, 4 rows/block ----
__global__ void xnorm_kernel(const float* __restrict__ x, u16* __restrict__ xn, int K) {
  int row = blockIdx.x * 4 + (threadIdx.x >> 6);
  int l = threadIdx.x & 63;
  const float4* p = reinterpret_cast<const float4*>(x + (size_t)row * K) + l * 2;
  float4 a = p[0], b = p[1];
  float s = a.x*a.x + a.y*a.y + a.z*a.z + a.w*a.w
          + b.x*b.x + b.y*b.y + b.z*b.z + b.w*b.w;
  #pragma unroll
  for (int m = 32; m >= 1; m >>= 1) s += __shfl_xor(s, m);
  float inv = rsqrtf(fmaxf(s, 1e-24f));
  u32 q0 = (u32)f2bf(a.x*inv) | ((u32)f2bf(a.y*inv) << 16);
  u32 q1 = (u32)f2bf(a.z*inv) | ((u32)f2bf(a.w*inv) << 16);
  u32 q2 = (u32)f2bf(b.x*inv) | ((u32)f2bf(b.y*inv) << 16);
  u32 q3 = (u32)f2bf(b.z*inv) | ((u32)f2bf(b.w*inv) << 16);
  *reinterpret_cast<uint4*>(xn + (size_t)row * K + l * 8) = make_uint4(q0, q1, q2, q3);
}

// ---- f32-exact target-class cosine per sample ----
__global__ void tgt_kernel(const float* __restrict__ x, const float* __restrict__ W,
                           const int* __restrict__ labels, float* __restrict__ tgtcos, int K) {
  int b = blockIdx.x;
  int l = threadIdx.x;
  int lab = labels[b];
  int labc = lab < 0 ? 0 : lab;
  const float4* px = reinterpret_cast<const float4*>(x + (size_t)b * K) + l * 2;
  const float4* pw = reinterpret_cast<const float4*>(W + (size_t)labc * K) + l * 2;
  float4 a0 = px[0], a1 = px[1], w0 = pw[0], w1 = pw[1];
  float dot = a0.x*w0.x + a0.y*w0.y + a0.z*w0.z + a0.w*w0.w
            + a1.x*w1.x + a1.y*w1.y + a1.z*w1.z + a1.w*w1.w;
  float sx = a0.x*a0.x + a0.y*a0.y + a0.z*a0.z + a0.w*a0.w
           + a1.x*a1.x + a1.y*a1.y + a1.z*a1.z + a1.w*a1.w;
  float sw = w0.x*w0.x + w0.y*w0.y + w0.z*w0.z + w0.w*w0.w
           + w1.x*w1.x + w1.y*w1.y + w1.z*w1.z + w1.w*w1.w;
  #pragma unroll
  for (int m = 32; m >= 1; m >>= 1) {
    dot += __shfl_xor(dot, m);
    sx  += __shfl_xor(sx, m);
    sw  += __shfl_xor(sw, m);
  }
  if (l == 0) {
    float cv = dot * rsqrtf(fmaxf(sx, 1e-24f)) * rsqrtf(fmaxf(sw, 1e-24f));
    tgtcos[b] = fminf(fmaxf(cv, -1.f), 1.f);
  }
}

// ---- fused GEMM: BOTH operands staged via global_load_lds (W as f32),
//      f32->bf16 cvt + row-sumsq folded into the MFMA phase ----
__global__ __launch_bounds__(256, 2) void gemm_gl(
    const u16* __restrict__ xn, const float* __restrict__ W,
    const int* __restrict__ labels,
    float* __restrict__ partials, int C, int K, int M) {
  __shared__ u16 sA[128 * 64];       // 16 KB, bf16, chunk=8 bf16, XOR (r&7)
  __shared__ float sBf[128 * 64];    // 32 KB, f32, chunk=4 f32, XOR (r&7) over 16 chunks
  __shared__ float bsum[2][128];
  __shared__ float sIw[128];
  __shared__ int slab[128];

  // XCD-bijective swizzle (m204), bm-fastest within a chunk
  int nwg = gridDim.x;
  int id = blockIdx.x;
  int q = nwg >> 3, r = nwg & 7;
  int xcd = id & 7, pos = id >> 3;
  int wg = (xcd < r ? xcd * (q + 1) : r * (q + 1) + (xcd - r) * q) + pos;
  const int bm = wg & 3, bn = wg >> 2;

  const int t = threadIdx.x;
  const int l = t & 63, wid = t >> 6;
  const int wm = wid >> 1, wn_ = wid & 1;
  const int n0 = bn * 128;
  if (t < 128) slab[t] = labels[bm * 128 + t];

  float ssq[4] = {0.f, 0.f, 0.f, 0.f};  // only meaningful for wm==0 waves
  f32x4 acc[4][4] = {};
  const int nkt = K >> 6;

  for (int kt = 0; kt < nkt; ++kt) {
    const int k0 = kt << 6;

    // --- stage A tile: 128x64 bf16, 4 x global_load_lds (src pre-swizzled) ---
    #pragma unroll
    for (int i = 0; i < 4; ++i) {
      int L = i * 256 + t;
      int rr = L >> 3;
      int cs = (L & 7) ^ (rr & 7);
      const u16* src = xn + (size_t)(bm * 128 + rr) * K + k0 + cs * 8;
      __builtin_amdgcn_global_load_lds(
          (const __attribute__((address_space(1))) void*)src,
          (__attribute__((address_space(3))) void*)(sA + (size_t)(i * 256 + (t & 192)) * 8),
          16, 0, 0);
    }
    // --- stage W tile: 128x64 f32, 8 x global_load_lds (src pre-swizzled) ---
    #pragma unroll
    for (int j = 0; j < 8; ++j) {
      int L = j * 256 + t;
      int rr = L >> 4;                 // N-row 0..127 (16 chunks of 16B per row)
      int cs = (L & 15) ^ (rr & 7);
      int gr = n0 + rr; gr = gr < C ? gr : C - 1;
      const float* src = W + (size_t)gr * K + k0 + cs * 4;
      __builtin_amdgcn_global_load_lds(
          (const __attribute__((address_space(1))) void*)src,
          (__attribute__((address_space(3))) void*)(sBf + (size_t)(j * 256 + (t & 192)) * 4),
          16, 0, 0);
    }

    __syncthreads();   // drain overlapped by co-resident block's MFMA phase

    // --- MFMA phase: B fragments read as f32, cvt in-phase, sumsq in-regs ---
    #pragma unroll
    for (int ks = 0; ks < 2; ++ks) {
      bf16x8 af[4], bfr[4];
      #pragma unroll
      for (int mi = 0; mi < 4; ++mi) {
        int row = wm * 64 + mi * 16 + (l & 15);
        int ch = ks * 4 + (l >> 4);
        af[mi] = *reinterpret_cast<const bf16x8*>(sA + row * 64 + ((ch ^ (row & 7)) * 8));
      }
      #pragma unroll
      for (int ni = 0; ni < 4; ++ni) {
        int row = wn_ * 64 + ni * 16 + (l & 15);
        int ch = ks * 4 + (l >> 4);
        int c1 = (2 * ch)     ^ (row & 7);
        int c2 = (2 * ch + 1) ^ (row & 7);
        f32x4 fa = *reinterpret_cast<const f32x4*>(sBf + row * 64 + c1 * 4);
        f32x4 fb = *reinterpret_cast<const f32x4*>(sBf + row * 64 + c2 * 4);
        if (wm == 0) {
          ssq[ni] += fa[0]*fa[0] + fa[1]*fa[1] + fa[2]*fa[2] + fa[3]*fa[3]
                   + fb[0]*fb[0] + fb[1]*fb[1] + fb[2]*fb[2] + fb[3]*fb[3];
        }
        uint4 u = make_uint4(cvtpk(fa[0], fa[1]), cvtpk(fa[2], fa[3]),
                             cvtpk(fb[0], fb[1]), cvtpk(fb[2], fb[3]));
        bfr[ni] = __builtin_bit_cast(bf16x8, u);
      }
      #pragma unroll
      for (int mi = 0; mi < 4; ++mi)
        #pragma unroll
        for (int ni = 0; ni < 4; ++ni)
          acc[mi][ni] = __builtin_amdgcn_mfma_f32_16x16x32_bf16(af[mi], bfr[ni], acc[mi][ni], 0, 0, 0);
    }
    __syncthreads();
  }

  // finalize inverse row norms: wm==0 waves covered every chunk of their rows once.
  // lanes l, l+16, l+32, l+48 share a row -> reduce over lane bits 4,5.
  if (wm == 0) {
    #pragma unroll
    for (int ni = 0; ni < 4; ++ni) {
      float s = ssq[ni];
      s += __shfl_xor(s, 16);
      s += __shfl_xor(s, 32);
      if ((l >> 4) == 0) sIw[wn_ * 64 + ni * 16 + l] = rsqrtf(fmaxf(s, 1e-24f));
    }
  }
  __syncthreads();

  // epilogue: cos -> exp(64 cos - 64), zero target column, per-row reduce
  float iw[4]; int colv[4];
  #pragma unroll
  for (int ni = 0; ni < 4; ++ni) {
    int cl = wn_ * 64 + ni * 16 + (l & 15);
    colv[ni] = n0 + cl;
    iw[ni] = sIw[cl];
  }
  #pragma unroll
  for (int mi = 0; mi < 4; ++mi) {
    #pragma unroll
    for (int rg = 0; rg < 4; ++rg) {
      int row_l = wm * 64 + mi * 16 + ((l >> 4) << 2) + rg;
      int labr = slab[row_l];
      float rs = 0.f;
      #pragma unroll
      for (int ni = 0; ni < 4; ++ni) {
        float cv = acc[mi][ni][rg] * iw[ni];
        cv = fminf(fmaxf(cv, -1.f), 1.f);
        float e = __expf(SCALEF * cv - SCALEF);
        bool keep = (colv[ni] < C) && (colv[ni] != labr);
        rs += keep ? e : 0.f;
      }
      rs += __shfl_xor(rs, 1);
      rs += __shfl_xor(rs, 2);
      rs += __shfl_xor(rs, 4);
      rs += __shfl_xor(rs, 8);
      if ((l & 15) == 0) bsum[wn_][row_l] = rs;
    }
  }
  __syncthreads();
  if (t < 128) {
    partials[(size_t)bn * M + bm * 128 + t] = bsum[0][t] + bsum[1][t];
  }
}

// ---- deterministic reduction of partials over N-blocks ----
__global__ void rowreduce_kernel(const float* __restrict__ partials, float* __restrict__ rowsum,
                                 int NBN, int M) {
  int b = blockIdx.x, t = threadIdx.x;
  float s = 0.f;
  for (int i = t; i < NBN; i += 256) s += partials[(size_t)i * M + b];
  __shared__ float sh[256];
  sh[t] = s; __syncthreads();
  for (int off = 128; off >= 1; off >>= 1) {
    if (t < off) sh[t] += sh[t + off];
    __syncthreads();
  }
  if (t == 0) rowsum[b] = sh[0];
}

// ---- final: per-sample nll + G-loss, single block ----
__global__ void final_kernel(const float* __restrict__ rowsum, const float* __restrict__ tgtcos,
                             const float* __restrict__ x_norm, const int* __restrict__ labels,
                             float* __restrict__ out, int Bn) {
  int t = threadIdx.x;
  float nll = 0.f, g = 0.f, vld = 0.f;
  if (t < Bn) {
    float a = x_norm[t];
    g = a * (1.0f / (U_A * U_A)) + 1.0f / a;
    int lab = labels[t];
    bool valid = (lab != -1);
    if (valid) {
      float ct = tgtcos[t];
      float margin = ((U_M - L_M) / (U_A - L_A)) * (a - L_A) + L_M;
      float theta = acosf(ct) + margin;
      float tl = SCALEF * cosf(theta);
      float se = rowsum[t] + __expf(tl - SCALEF);
      float lse = SCALEF + logf(se);
      nll = lse - tl;
      vld = 1.f;
    }
  }
  __shared__ float s1[512], s2[512], s3[512];
  s1[t] = nll; s2[t] = g; s3[t] = vld;
  __syncthreads();
  for (int off = 256; off >= 1; off >>= 1) {
    if (t < off) { s1[t] += s1[t + off]; s2[t] += s2[t + off]; s3[t] += s3[t + off]; }
    __syncthreads();
  }
  if (t == 0) {
    float ce = s1[0] / fmaxf(s3[0], 1.f);
    out[0] = ce + LAMBDA_G * (s2[0] / (float)Bn);
  }
}

extern "C" void kernel_launch(void* const* d_in, const int* in_sizes, int n_in,
                              void* d_out, int out_size, void* d_ws, size_t ws_size,
                              hipStream_t stream) {
  const float* x      = (const float*)d_in[0];
  const float* x_norm = (const float*)d_in[1];
  const int*   labels = (const int*)d_in[2];
  const float* W      = (const float*)d_in[3];
  float* out = (float*)d_out;

  const int B = in_sizes[1];             // 512
  const int D = in_sizes[0] / B;         // 512
  const int C = in_sizes[3] / D;         // 100000
  const int NBN = (C + 127) / 128;       // 782

  char* ws = (char*)d_ws;
  size_t o_xn   = 0;
  size_t o_tgt  = o_xn + (size_t)B * D * 2;
  size_t o_rows = o_tgt + (size_t)B * 4;
  size_t o_part = o_rows + (size_t)B * 4;

  u16*   xn       = (u16*)(ws + o_xn);
  float* tgtcos   = (float*)(ws + o_tgt);
  float* rowsum   = (float*)(ws + o_rows);
  float* partials = (float*)(ws + o_part);

  hipLaunchKernelGGL(xnorm_kernel, dim3(B / 4), dim3(256), 0, stream, x, xn, D);
  hipLaunchKernelGGL(tgt_kernel, dim3(B), dim3(64), 0, stream, x, W, labels, tgtcos, D);
  hipLaunchKernelGGL(gemm_gl, dim3(NBN * (B / 128)), dim3(256), 0, stream,
                     xn, W, labels, partials, C, D, B);
  hipLaunchKernelGGL(rowreduce_kernel, dim3(B), dim3(256), 0, stream, partials, rowsum, NBN, B);
  hipLaunchKernelGGL(final_kernel, dim3(1), dim3(B), 0, stream, rowsum, tgtcos, x_norm, labels, out, B);
}